// Round 4
// baseline (184.551 us; speedup 1.0000x reference)
//
#include <hip/hip_runtime.h>
#include <hip/hip_bf16.h>

// Conv 3x3, C_IN=128, C_OUT=256, H=W=256, pad=1, stride=1, batch=1.
// R4: B-window staged in LDS ONCE per kh (3 kw phases share it, barrier-free inner
//     loop, 2 barriers/kh); A loaded from global in a lane-exact coalesced layout
//     Wr2[khw][g][kk][quad][l16][8] (1 KB per frag instruction, L2-resident).
//     MFMA floor 18.6 us; LDS floor ~13.5 us -> MFMA-bound by design.

typedef short bf16x8 __attribute__((ext_vector_type(8)));    // 8 bf16 = 4 VGPRs
typedef float f32x4 __attribute__((ext_vector_type(4)));
typedef unsigned short u16x4 __attribute__((ext_vector_type(4)));
typedef unsigned short u16x8 __attribute__((ext_vector_type(8)));

#define CIN   128
#define COUT  256
#define HH    256
#define WW    256
#define HP    258                 // padded
#define ROWP  (HP * CIN)          // padded row stride in elems = 33024

static __device__ __forceinline__ unsigned short f2bf(float v) {
    __hip_bfloat16 b = __float2bfloat16(v);
    return *reinterpret_cast<unsigned short*>(&b);
}

static __device__ __forceinline__ void gload_lds16(const unsigned short* g, unsigned short* l) {
    __builtin_amdgcn_global_load_lds(
        (const __attribute__((address_space(1))) unsigned int*)g,
        (__attribute__((address_space(3))) unsigned int*)l, 16, 0, 0);
}

// ---------------- pre-pass 1: x NCHW fp32 -> padded NHWC bf16 + edge zeroing ---------
__global__ __launch_bounds__(256) void xpose_kernel(const float* __restrict__ x,
                                                    unsigned short* __restrict__ xb) {
    int bid = blockIdx.x;
    int h  = bid >> 2;
    int w0 = (bid & 3) * 64;
    __shared__ unsigned short tile[CIN * 72];   // [ci][w], w padded 64->72
    int t = threadIdx.x;

    // fused edge zeroing: first 65 blocks cover the 16448 vec8 border tasks
    if (bid < 65) {
        int i = bid * 256 + t;
        if (i < 16448) {
            u16x8 z = {0, 0, 0, 0, 0, 0, 0, 0};
            int off;
            if (i < 8256) {
                int r   = (i >= 4128) ? 1 : 0;
                int rem = i - r * 4128;
                off = (r * 257) * ROWP + rem * 8;
            } else {
                int j   = i - 8256;           // 0..8191
                int col = j >> 12;            // 0 or 1
                int rem = j & 4095;
                int hp  = (rem >> 4) + 1;     // 1..256
                int c8  = rem & 15;
                off = hp * ROWP + (col * 257) * CIN + c8 * 8;
            }
            *(u16x8*)(&xb[off]) = z;
        }
    }

    // phase 1: coalesced read along w (float4), write bf16x4 to LDS [ci][w]
    int wq = t & 15;          // 16 * float4 = 64 w
    int cib = t >> 4;         // 16 ci per pass
    for (int c0 = 0; c0 < CIN; c0 += 16) {
        int ci = c0 + cib;
        float4 v = *(const float4*)(x + ci * (HH * WW) + h * WW + w0 + wq * 4);
        u16x4 p;
        p.x = f2bf(v.x); p.y = f2bf(v.y); p.z = f2bf(v.z); p.w = f2bf(v.w);
        *(u16x4*)(&tile[ci * 72 + wq * 4]) = p;
    }
    __syncthreads();

    // phase 2: w-major lane mapping -> conflict-free LDS reads; 16B stores
    for (int it = 0; it < 4; ++it) {
        int idx = it * 256 + t;       // 0..1023
        int w  = idx & 63;            // varies within wave
        int c8 = idx >> 6;            // 0..15, wave-uniform
        u16x8 o;
        #pragma unroll
        for (int j = 0; j < 8; ++j)
            o[j] = tile[(c8 * 8 + j) * 72 + w];
        int dst = ((h + 1) * HP + (w0 + w + 1)) * CIN + c8 * 8;
        *(u16x8*)(&xb[dst]) = o;
    }
}

// ---------------- pre-pass 2: weight -> lane-exact MFMA A layout ---------------------
// Wr2 element index o = ((((khw*16 + gg)*4 + kk)*4 + quad)*16 + l16)*8 + j
//   holds W[co = gg*16+l16][ci = (kk*4+quad)*8 + j] for plane khw.
// A-frag (khw, gg, kk) load: 64 lanes read contiguous 1 KB at offset ((khw*16+gg)*4+kk)*512.
__global__ __launch_bounds__(256) void wreorder_kernel(const float* __restrict__ w,
                                                       unsigned short* __restrict__ wr2) {
    int o = blockIdx.x * 256 + threadIdx.x;   // 294912 total
    int j    = o & 7;
    int l16  = (o >> 3) & 15;
    int quad = (o >> 7) & 3;
    int kk   = (o >> 9) & 3;
    int gg   = (o >> 11) & 15;
    int khw  = o >> 15;                       // 0..8
    int co = gg * 16 + l16;
    int ci = (kk * 4 + quad) * 8 + j;
    wr2[o] = f2bf(w[co * (CIN * 9) + ci * 9 + khw]);
}

// ---------------- main: implicit-GEMM MFMA conv --------------------------------------
// block tile: 128 co x 128 spatial (one h, half of w). 4 waves (2x2), each 64x64.
// Per kh: stage 130-col B window (33.3 KB) once; 3 kw phases x 4 kk steps, barrier-free.
// B frag: col = n + kw, chunk = kk*4+quad, slot = chunk ^ (col&15) (XOR swizzle).
__global__ __launch_bounds__(256) void conv_mfma_kernel(const unsigned short* __restrict__ xb,
                                                        const unsigned short* __restrict__ wr2,
                                                        const float* __restrict__ bias,
                                                        float* __restrict__ out) {
    __shared__ unsigned short Bw[130 * 128];   // 33,280 B: [col 0..129][ci], 16B-chunk swizzled

    int bid  = blockIdx.x;        // 1024
    int co_t = bid & 1;
    int wh   = (bid >> 1) & 1;
    int h    = bid >> 2;          // 0..255
    int co0  = co_t * 128;
    int p0   = h * WW + wh * 128;

    int t    = threadIdx.x;
    int wave = t >> 6;
    int lane = t & 63;
    int wm   = wave >> 1;         // co half (0/1)
    int wn   = wave & 1;          // spatial half (0/1)
    int quad = lane >> 4;
    int l16  = lane & 15;

    f32x4 acc[4][4];
    #pragma unroll
    for (int mi = 0; mi < 4; ++mi)
        #pragma unroll
        for (int ni = 0; ni < 4; ++ni)
            acc[mi][ni] = (f32x4){0.f, 0.f, 0.f, 0.f};

    // A-frag base group index for this wave: gg = co_t*8 + wm*4 + mi
    int ggb = co_t * 8 + wm * 4;

    for (int kh = 0; kh < 3; ++kh) {
        __syncthreads();   // previous kh's Bw consumers done
        // stage B window: 130 cols x 128 ci = 2080 16B-chunks, slot s holds chunk s^(col&15)
        {
            const unsigned short* xrow = xb + (size_t)((h + kh) * HP + wh * 128) * CIN;
            #pragma unroll
            for (int it = 0; it < 8; ++it) {
                int seg = it * 256 + t;
                int col = seg >> 4;
                int s   = seg & 15;
                int c   = s ^ (col & 15);
                gload_lds16(xrow + col * CIN + c * 8, &Bw[seg * 8]);
            }
            if (t < 32) {     // tail: segs 2048..2079
                int seg = 2048 + t;
                int col = seg >> 4;
                int s   = seg & 15;
                int c   = s ^ (col & 15);
                gload_lds16(xrow + col * CIN + c * 8, &Bw[seg * 8]);
            }
        }
        // prefetch kw=0 A frags BEFORE the barrier: the vmcnt(0) drain delivers them free
        bf16x8 af[4][4];    // [kk][mi]
        {
            int khw = kh * 3;
            const unsigned short* ab = wr2 + (size_t)khw * 16 * 2048 + (size_t)lane * 8;
            #pragma unroll
            for (int kk = 0; kk < 4; ++kk)
                #pragma unroll
                for (int mi = 0; mi < 4; ++mi)
                    af[kk][mi] = *(const bf16x8*)(ab + ((ggb + mi) * 4 + kk) * 512);
        }
        __syncthreads();   // Bw ready

        for (int kw = 0; kw < 3; ++kw) {
            if (kw > 0) {
                int khw = kh * 3 + kw;
                const unsigned short* ab = wr2 + (size_t)khw * 16 * 2048 + (size_t)lane * 8;
                #pragma unroll
                for (int kk = 0; kk < 4; ++kk)
                    #pragma unroll
                    for (int mi = 0; mi < 4; ++mi)
                        af[kk][mi] = *(const bf16x8*)(ab + ((ggb + mi) * 4 + kk) * 512);
            }
            #pragma unroll
            for (int kk = 0; kk < 4; ++kk) {
                bf16x8 bfr[4];
                #pragma unroll
                for (int ni = 0; ni < 4; ++ni) {
                    int col = wn * 64 + ni * 16 + l16 + kw;
                    int slot = (kk * 4 + quad) ^ (col & 15);
                    bfr[ni] = *(bf16x8*)(&Bw[col * 128 + slot * 8]);
                }
                #pragma unroll
                for (int mi = 0; mi < 4; ++mi)
                    #pragma unroll
                    for (int ni = 0; ni < 4; ++ni)
                        acc[mi][ni] = __builtin_amdgcn_mfma_f32_16x16x32_bf16(
                            af[kk][mi], bfr[ni], acc[mi][ni], 0, 0, 0);
            }
        }
    }

    // epilogue: C/D layout col(spatial)=lane&15, row(co)=quad*4+reg
    #pragma unroll
    for (int mi = 0; mi < 4; ++mi) {
        #pragma unroll
        for (int r = 0; r < 4; ++r) {
            int co = co0 + wm * 64 + mi * 16 + quad * 4 + r;
            float b = bias[co];
            float* orow = out + co * (HH * WW) + p0 + wn * 64 + l16;
            #pragma unroll
            for (int ni = 0; ni < 4; ++ni)
                orow[ni * 16] = acc[mi][ni][r] + b;
        }
    }
}

extern "C" void kernel_launch(void* const* d_in, const int* in_sizes, int n_in,
                              void* d_out, int out_size, void* d_ws, size_t ws_size,
                              hipStream_t stream) {
    const float* x    = (const float*)d_in[0];   // [1,128,256,256]
    const float* w    = (const float*)d_in[1];   // [256,128,3,3]
    const float* bias = (const float*)d_in[2];   // [256]
    float* out        = (float*)d_out;           // [1,256,256,256]

    unsigned short* xb  = (unsigned short*)d_ws;             // 258*258*128 bf16 = 17,040,384 B
    unsigned short* wr2 = xb + (size_t)HP * HP * CIN;        // 9*16*2048 bf16   =    589,824 B

    xpose_kernel<<<dim3(1024), dim3(256), 0, stream>>>(x, xb);
    wreorder_kernel<<<dim3(1152), dim3(256), 0, stream>>>(w, wr2);
    conv_mfma_kernel<<<dim3(1024), dim3(256), 0, stream>>>(xb, wr2, bias, out);
}

// Round 6
// 137.858 us; speedup vs baseline: 1.3387x; 1.3387x over previous
//
#include <hip/hip_runtime.h>
#include <hip/hip_bf16.h>

// Conv 3x3, C_IN=128, C_OUT=256, H=W=256, pad=1, stride=1, batch=1.
// R6: TWO dispatches. prep_kernel = fused edge-zero + weight-reorder + xpose
//     (disjoint per-bid work, all three verified in R2). conv = R2 structure
//     verbatim (52.9 us, MfmaUtil 27.5%, 0 bank conflicts — best measured).
//     R3/R4 (A-from-global) regressed ~+40us; R5 (cooperative) failed to launch.

typedef short bf16x8 __attribute__((ext_vector_type(8)));    // 8 bf16 = 4 VGPRs
typedef float f32x4 __attribute__((ext_vector_type(4)));
typedef unsigned short u16x4 __attribute__((ext_vector_type(4)));
typedef unsigned short u16x8 __attribute__((ext_vector_type(8)));

#define CIN   128
#define COUT  256
#define HH    256
#define WW    256
#define HP    258                 // padded
#define ROWP  (HP * CIN)          // padded row stride in elems = 33024

static __device__ __forceinline__ unsigned short f2bf(float v) {
    __hip_bfloat16 b = __float2bfloat16(v);
    return *reinterpret_cast<unsigned short*>(&b);
}

static __device__ __forceinline__ void gload_lds16(const unsigned short* g, unsigned short* l) {
    __builtin_amdgcn_global_load_lds(
        (const __attribute__((address_space(1))) unsigned int*)g,
        (__attribute__((address_space(3))) unsigned int*)l, 16, 0, 0);
}

// ---------------- dispatch 1: fused prepass (edge zero + wreorder + xpose) -----------
// grid: 1024 blocks x 256 threads (one 64-w xpose tile per block)
__global__ __launch_bounds__(256) void prep_kernel(const float* __restrict__ x,
                                                   const float* __restrict__ w,
                                                   unsigned short* __restrict__ xb,
                                                   unsigned short* __restrict__ wr) {
    int bid = blockIdx.x;
    int t   = threadIdx.x;

    // (a) edge zeroing: blocks 0..64 cover the 16448 vec8 border tasks
    if (bid < 65) {
        int i = bid * 256 + t;
        if (i < 16448) {
            u16x8 z = {0, 0, 0, 0, 0, 0, 0, 0};
            int off;
            if (i < 8256) {
                int r   = (i >= 4128) ? 1 : 0;
                int rem = i - r * 4128;
                off = (r * 257) * ROWP + rem * 8;
            } else {
                int j   = i - 8256;           // 0..8191
                int col = j >> 12;            // 0 or 1
                int rem = j & 4095;
                int hp  = (rem >> 4) + 1;     // 1..256
                int c8  = rem & 15;
                off = hp * ROWP + (col * 257) * CIN + c8 * 8;
            }
            *(u16x8*)(&xb[off]) = z;
        }
    }

    // (b) weight reorder: blocks 0..127, one thread per (co,ci), coalesced
    if (bid < 128) {
        int p = bid * 256 + t;    // 0..32767 = co*128+ci
        const float* src = w + p * 9;
        #pragma unroll
        for (int khw = 0; khw < 9; ++khw)
            wr[khw * (COUT * CIN) + p] = f2bf(src[khw]);
    }

    // (c) xpose: NCHW fp32 -> padded NHWC bf16, one 64-w tile per block
    int h  = bid >> 2;
    int w0 = (bid & 3) * 64;
    __shared__ unsigned short tile[CIN * 72];   // [ci][w], w padded 64->72

    int wq  = t & 15;          // 16 * float4 = 64 w
    int cib = t >> 4;          // 16 ci per pass
    for (int c0 = 0; c0 < CIN; c0 += 16) {
        int ci = c0 + cib;
        float4 v = *(const float4*)(x + ci * (HH * WW) + h * WW + w0 + wq * 4);
        u16x4 p;
        p.x = f2bf(v.x); p.y = f2bf(v.y); p.z = f2bf(v.z); p.w = f2bf(v.w);
        *(u16x4*)(&tile[ci * 72 + wq * 4]) = p;
    }
    __syncthreads();

    for (int it = 0; it < 4; ++it) {
        int idx = it * 256 + t;       // 0..1023
        int ww_ = idx & 63;           // varies within wave (conflict-free LDS reads)
        int c8  = idx >> 6;           // 0..15, wave-uniform
        u16x8 o;
        #pragma unroll
        for (int j = 0; j < 8; ++j)
            o[j] = tile[(c8 * 8 + j) * 72 + ww_];
        int dst = ((h + 1) * HP + (w0 + ww_ + 1)) * CIN + c8 * 8;
        *(u16x8*)(&xb[dst]) = o;
    }
}

// ---------------- dispatch 2: implicit-GEMM MFMA conv (R2 structure, unchanged) ------
// block tile: 128 co x 128 spatial. 4 waves (2x2), each 64x64.
// K-loop: 9 khw x 2 ci-chunks of 64. LDS tiles [128][64] bf16 via global_load_lds,
// XOR swizzle (slot = chunk ^ (row&7)) -> 0 bank conflicts. 32 KB LDS.
__global__ __launch_bounds__(256) void conv_mfma_kernel(const unsigned short* __restrict__ xb,
                                                        const unsigned short* __restrict__ wr,
                                                        const float* __restrict__ bias,
                                                        float* __restrict__ out) {
    __shared__ unsigned short As[128 * 64];   // [co][k] swizzled, 16384 B
    __shared__ unsigned short Bs[128 * 64];   // [spatial][k] swizzled, 16384 B

    int bid  = blockIdx.x;        // 1024
    int co_t = bid & 1;
    int wh   = (bid >> 1) & 1;
    int h    = bid >> 2;          // 0..255
    int co0  = co_t * 128;
    int p0   = h * WW + wh * 128;

    int t    = threadIdx.x;
    int wave = t >> 6;
    int lane = t & 63;
    int wm   = wave >> 1;         // co half (0/1)
    int wn   = wave & 1;          // spatial half (0/1)
    int quad = lane >> 4;
    int l16  = lane & 15;
    int sw   = l16 & 7;           // fragment-read swizzle (= row&7)

    int lr = lane >> 3;           // staging: local row 0..7
    int s  = lane & 7;            // staging: slot
    int cs = (s ^ lr) * 8;        // staging: source k-offset (elems)

    f32x4 acc[4][4];
    #pragma unroll
    for (int mi = 0; mi < 4; ++mi)
        #pragma unroll
        for (int ni = 0; ni < 4; ++ni)
            acc[mi][ni] = (f32x4){0.f, 0.f, 0.f, 0.f};

    for (int kh = 0; kh < 3; ++kh) {
        for (int kw = 0; kw < 3; ++kw) {
            int khw = kh * 3 + kw;
            const unsigned short* xsrc = xb + (size_t)((h + kh) * HP + wh * 128 + kw) * CIN;
            const unsigned short* wsrc = wr + (size_t)khw * (COUT * CIN) + co0 * CIN;
            for (int cc = 0; cc < 2; ++cc) {
                int kofs = cc * 64;
                __syncthreads();
                #pragma unroll
                for (int it = 0; it < 4; ++it) {
                    int cid = wave * 4 + it;          // 8-row chunk id
                    int r   = cid * 8 + lr;
                    int ge  = kofs + cs;
                    gload_lds16(wsrc + r * CIN + ge, &As[cid * 512]);
                    gload_lds16(xsrc + r * CIN + ge, &Bs[cid * 512]);
                }
                __syncthreads();
                #pragma unroll
                for (int kk = 0; kk < 2; ++kk) {
                    bf16x8 af[4], bfr[4];
                    #pragma unroll
                    for (int mi = 0; mi < 4; ++mi) {
                        int row = wm * 64 + mi * 16 + l16;
                        af[mi] = *(bf16x8*)(&As[row * 64 + ((kk * 4 + quad) ^ sw) * 8]);
                    }
                    #pragma unroll
                    for (int ni = 0; ni < 4; ++ni) {
                        int row = wn * 64 + ni * 16 + l16;
                        bfr[ni] = *(bf16x8*)(&Bs[row * 64 + ((kk * 4 + quad) ^ sw) * 8]);
                    }
                    #pragma unroll
                    for (int mi = 0; mi < 4; ++mi)
                        #pragma unroll
                        for (int ni = 0; ni < 4; ++ni)
                            acc[mi][ni] = __builtin_amdgcn_mfma_f32_16x16x32_bf16(
                                af[mi], bfr[ni], acc[mi][ni], 0, 0, 0);
                }
            }
        }
    }

    // epilogue: C/D layout col(spatial)=lane&15, row(co)=quad*4+reg
    #pragma unroll
    for (int mi = 0; mi < 4; ++mi) {
        #pragma unroll
        for (int r = 0; r < 4; ++r) {
            int co = co0 + wm * 64 + mi * 16 + quad * 4 + r;
            float b = bias[co];
            float* orow = out + (size_t)co * (HH * WW) + p0 + wn * 64 + l16;
            #pragma unroll
            for (int ni = 0; ni < 4; ++ni)
                orow[ni * 16] = acc[mi][ni][r] + b;
        }
    }
}

extern "C" void kernel_launch(void* const* d_in, const int* in_sizes, int n_in,
                              void* d_out, int out_size, void* d_ws, size_t ws_size,
                              hipStream_t stream) {
    const float* x    = (const float*)d_in[0];   // [1,128,256,256]
    const float* w    = (const float*)d_in[1];   // [256,128,3,3]
    const float* bias = (const float*)d_in[2];   // [256]
    float* out        = (float*)d_out;           // [1,256,256,256]

    unsigned short* xb = (unsigned short*)d_ws;              // 258*258*128 bf16 = 17,040,384 B
    unsigned short* wr = xb + (size_t)HP * HP * CIN;         // 9*256*128 bf16  =    589,824 B

    prep_kernel<<<dim3(1024), dim3(256), 0, stream>>>(x, w, xb, wr);
    conv_mfma_kernel<<<dim3(1024), dim3(256), 0, stream>>>(xb, wr, bias, out);
}

// Round 7
// 135.851 us; speedup vs baseline: 1.3585x; 1.0148x over previous
//
#include <hip/hip_runtime.h>
#include <hip/hip_bf16.h>

// Conv 3x3, C_IN=128, C_OUT=256, H=W=256, pad=1, stride=1, batch=1.
// R7: restructured conv K-loop. Per kh: B window (130 cols, 33.3 KB) staged ONCE;
//     per khw: full A plane (128x128, 32 KB) staged; 64 MFMA per barrier pair
//     (9 pairs vs R2's 36). All staging via global_load_lds 16B + XOR swizzle.
//     LDS 66 KB -> 2 blocks/CU. Prep dispatch unchanged from R6.

typedef short bf16x8 __attribute__((ext_vector_type(8)));    // 8 bf16 = 4 VGPRs
typedef float f32x4 __attribute__((ext_vector_type(4)));
typedef unsigned short u16x4 __attribute__((ext_vector_type(4)));
typedef unsigned short u16x8 __attribute__((ext_vector_type(8)));

#define CIN   128
#define COUT  256
#define HH    256
#define WW    256
#define HP    258                 // padded
#define ROWP  (HP * CIN)          // padded row stride in elems = 33024

static __device__ __forceinline__ unsigned short f2bf(float v) {
    __hip_bfloat16 b = __float2bfloat16(v);
    return *reinterpret_cast<unsigned short*>(&b);
}

static __device__ __forceinline__ void gload_lds16(const unsigned short* g, unsigned short* l) {
    __builtin_amdgcn_global_load_lds(
        (const __attribute__((address_space(1))) unsigned int*)g,
        (__attribute__((address_space(3))) unsigned int*)l, 16, 0, 0);
}

// ---------------- dispatch 1: fused prepass (edge zero + wreorder + xpose) -----------
// grid: 1024 blocks x 256 threads (one 64-w xpose tile per block)
__global__ __launch_bounds__(256) void prep_kernel(const float* __restrict__ x,
                                                   const float* __restrict__ w,
                                                   unsigned short* __restrict__ xb,
                                                   unsigned short* __restrict__ wr) {
    int bid = blockIdx.x;
    int t   = threadIdx.x;

    // (a) edge zeroing: blocks 0..64 cover the 16448 vec8 border tasks
    if (bid < 65) {
        int i = bid * 256 + t;
        if (i < 16448) {
            u16x8 z = {0, 0, 0, 0, 0, 0, 0, 0};
            int off;
            if (i < 8256) {
                int r   = (i >= 4128) ? 1 : 0;
                int rem = i - r * 4128;
                off = (r * 257) * ROWP + rem * 8;
            } else {
                int j   = i - 8256;           // 0..8191
                int col = j >> 12;            // 0 or 1
                int rem = j & 4095;
                int hp  = (rem >> 4) + 1;     // 1..256
                int c8  = rem & 15;
                off = hp * ROWP + (col * 257) * CIN + c8 * 8;
            }
            *(u16x8*)(&xb[off]) = z;
        }
    }

    // (b) weight reorder: blocks 0..127, one thread per (co,ci), coalesced
    if (bid < 128) {
        int p = bid * 256 + t;    // 0..32767 = co*128+ci
        const float* src = w + p * 9;
        #pragma unroll
        for (int khw = 0; khw < 9; ++khw)
            wr[khw * (COUT * CIN) + p] = f2bf(src[khw]);
    }

    // (c) xpose: NCHW fp32 -> padded NHWC bf16, one 64-w tile per block
    int h  = bid >> 2;
    int w0 = (bid & 3) * 64;
    __shared__ unsigned short tile[CIN * 72];   // [ci][w], w padded 64->72

    int wq  = t & 15;          // 16 * float4 = 64 w
    int cib = t >> 4;          // 16 ci per pass
    for (int c0 = 0; c0 < CIN; c0 += 16) {
        int ci = c0 + cib;
        float4 v = *(const float4*)(x + ci * (HH * WW) + h * WW + w0 + wq * 4);
        u16x4 p;
        p.x = f2bf(v.x); p.y = f2bf(v.y); p.z = f2bf(v.z); p.w = f2bf(v.w);
        *(u16x4*)(&tile[ci * 72 + wq * 4]) = p;
    }
    __syncthreads();

    for (int it = 0; it < 4; ++it) {
        int idx = it * 256 + t;       // 0..1023
        int ww_ = idx & 63;           // varies within wave (conflict-free LDS reads)
        int c8  = idx >> 6;           // 0..15, wave-uniform
        u16x8 o;
        #pragma unroll
        for (int j = 0; j < 8; ++j)
            o[j] = tile[(c8 * 8 + j) * 72 + ww_];
        int dst = ((h + 1) * HP + (w0 + ww_ + 1)) * CIN + c8 * 8;
        *(u16x8*)(&xb[dst]) = o;
    }
}

// ---------------- dispatch 2: implicit-GEMM MFMA conv, per-kh B window ---------------
// block tile: 128 co x 128 spatial. 4 waves (2x2), each 64x64.
// Bw[col 0..129][ci 0..127]: 16B chunk c of col stored at slot c^(col&15).
// As[row 0..127][ci 0..127]: 16B chunk c of row stored at slot c^(row&15).
// Frag reads hit slot*4 mod 32 banks -> 2-way aliasing (free).
__global__ __launch_bounds__(256) void conv_mfma_kernel(const unsigned short* __restrict__ xb,
                                                        const unsigned short* __restrict__ wr,
                                                        const float* __restrict__ bias,
                                                        float* __restrict__ out) {
    __shared__ unsigned short Bw[130 * 128];   // 33280 B
    __shared__ unsigned short As[128 * 128];   // 32768 B

    int bid  = blockIdx.x;        // 1024
    int co_t = bid & 1;
    int wh   = (bid >> 1) & 1;
    int h    = bid >> 2;          // 0..255
    int co0  = co_t * 128;
    int p0   = h * WW + wh * 128;

    int t    = threadIdx.x;
    int wave = t >> 6;
    int lane = t & 63;
    int wm   = wave >> 1;         // co half (0/1)
    int wn   = wave & 1;          // spatial half (0/1)
    int quad = lane >> 4;
    int l16  = lane & 15;

    f32x4 acc[4][4];
    #pragma unroll
    for (int mi = 0; mi < 4; ++mi)
        #pragma unroll
        for (int ni = 0; ni < 4; ++ni)
            acc[mi][ni] = (f32x4){0.f, 0.f, 0.f, 0.f};

    for (int kh = 0; kh < 3; ++kh) {
        for (int kw = 0; kw < 3; ++kw) {
            int khw = kh * 3 + kw;
            __syncthreads();   // previous phase's LDS consumers done
            if (kw == 0) {
                // stage B window: 130 cols x 16 chunks = 2080 segs of 16B
                const unsigned short* xrow = xb + (size_t)((h + kh) * HP + wh * 128) * CIN;
                #pragma unroll
                for (int it = 0; it < 8; ++it) {
                    int seg = it * 256 + t;
                    int col = seg >> 4;
                    int s   = seg & 15;
                    int c   = s ^ (col & 15);
                    gload_lds16(xrow + col * CIN + c * 8, &Bw[seg * 8]);
                }
                if (t < 32) {
                    int seg = 2048 + t;
                    int col = seg >> 4;
                    int s   = seg & 15;
                    int c   = s ^ (col & 15);
                    gload_lds16(xrow + col * CIN + c * 8, &Bw[seg * 8]);
                }
            }
            // stage A plane for this khw: 128 rows x 16 chunks = 2048 segs
            {
                const unsigned short* wsrc = wr + (size_t)khw * (COUT * CIN) + co0 * CIN;
                #pragma unroll
                for (int it = 0; it < 8; ++it) {
                    int seg = it * 256 + t;
                    int r   = seg >> 4;
                    int s   = seg & 15;
                    int c   = s ^ (r & 15);
                    gload_lds16(wsrc + r * CIN + c * 8, &As[seg * 8]);
                }
            }
            __syncthreads();   // DMA drained (compiler emits vmcnt(0) before barrier)
            // compute: 4 kk x 16 MFMA = 64 MFMA per barrier pair
            #pragma unroll
            for (int kk = 0; kk < 4; ++kk) {
                int chunk = kk * 4 + quad;
                bf16x8 af[4], bfr[4];
                #pragma unroll
                for (int mi = 0; mi < 4; ++mi) {
                    int row = wm * 64 + mi * 16 + l16;
                    af[mi] = *(bf16x8*)(&As[row * 128 + (chunk ^ l16) * 8]);
                }
                #pragma unroll
                for (int ni = 0; ni < 4; ++ni) {
                    int col = wn * 64 + ni * 16 + l16 + kw;
                    bfr[ni] = *(bf16x8*)(&Bw[col * 128 + (chunk ^ (col & 15)) * 8]);
                }
                #pragma unroll
                for (int mi = 0; mi < 4; ++mi)
                    #pragma unroll
                    for (int ni = 0; ni < 4; ++ni)
                        acc[mi][ni] = __builtin_amdgcn_mfma_f32_16x16x32_bf16(
                            af[mi], bfr[ni], acc[mi][ni], 0, 0, 0);
            }
        }
    }

    // epilogue: C/D layout col(spatial)=lane&15, row(co)=quad*4+reg
    #pragma unroll
    for (int mi = 0; mi < 4; ++mi) {
        #pragma unroll
        for (int r = 0; r < 4; ++r) {
            int co = co0 + wm * 64 + mi * 16 + quad * 4 + r;
            float b = bias[co];
            float* orow = out + (size_t)co * (HH * WW) + p0 + wn * 64 + l16;
            #pragma unroll
            for (int ni = 0; ni < 4; ++ni)
                orow[ni * 16] = acc[mi][ni][r] + b;
        }
    }
}

extern "C" void kernel_launch(void* const* d_in, const int* in_sizes, int n_in,
                              void* d_out, int out_size, void* d_ws, size_t ws_size,
                              hipStream_t stream) {
    const float* x    = (const float*)d_in[0];   // [1,128,256,256]
    const float* w    = (const float*)d_in[1];   // [256,128,3,3]
    const float* bias = (const float*)d_in[2];   // [256]
    float* out        = (float*)d_out;           // [1,256,256,256]

    unsigned short* xb = (unsigned short*)d_ws;              // 258*258*128 bf16 = 17,040,384 B
    unsigned short* wr = xb + (size_t)HP * HP * CIN;         // 9*256*128 bf16  =    589,824 B

    prep_kernel<<<dim3(1024), dim3(256), 0, stream>>>(x, w, xb, wr);
    conv_mfma_kernel<<<dim3(1024), dim3(256), 0, stream>>>(xb, wr, bias, out);
}